// Round 1
// baseline (591.314 us; speedup 1.0000x reference)
//
#include <hip/hip_runtime.h>

typedef unsigned short u16;
typedef unsigned int u32;
typedef __bf16 bf16x8 __attribute__((ext_vector_type(8)));
typedef float f32x4 __attribute__((ext_vector_type(4)));

// Problem constants
// S=2048 HID=4096 H=32 HKV=8 D=96 DFULL=128, NQKV = 32*96 + 2*8*96 = 4608
#define SCALE_Q 0.08838834764831845f  // 128^-0.5

__device__ __forceinline__ u16 f2bf(float f) {
  u32 u = __builtin_bit_cast(u32, f);
  u += 0x7fffu + ((u >> 16) & 1u);  // RNE
  return (u16)(u >> 16);
}

// ---------------- f32 -> bf16 convert (vectorized x4) ----------------
__global__ __launch_bounds__(256) void cvt_kernel(const float* __restrict__ src,
                                                  u16* __restrict__ dst, int n4) {
  int i = blockIdx.x * 256 + threadIdx.x;
  if (i >= n4) return;
  float4 v = ((const float4*)src)[i];
  u32 lo = (u32)f2bf(v.x) | ((u32)f2bf(v.y) << 16);
  u32 hi = (u32)f2bf(v.z) | ((u32)f2bf(v.w) << 16);
  ((uint2*)dst)[i] = make_uint2(lo, hi);
}

// ---------------- GEMM  C[M][N] = A[M][K] * B[N][K]^T  (bf16 in, f32 out) ----
// 128x128 tile, BK=64, 4 waves (2x2 of 64x64), 16x16x32 MFMA.
// LDS layout: [row][8 chunks of 8 bf16], chunk col XOR-swizzled by (row&7):
// conflict-free for both ds_write_b128 staging and ds_read_b128 fragment reads.
__global__ __launch_bounds__(256) void gemm_bt(const u16* __restrict__ A,
                                               const u16* __restrict__ B,
                                               float* __restrict__ C,
                                               int M, int N, int K) {
  __shared__ u16 As[128 * 64];
  __shared__ u16 Bs[128 * 64];
  const int tid = threadIdx.x;
  const int w = tid >> 6, lane = tid & 63, quad = lane >> 4, c16 = lane & 15;
  const int m0 = blockIdx.y * 128, n0 = blockIdx.x * 128;
  const int wm = (w & 1) * 64, wn = (w >> 1) * 64;
  const int srow = tid >> 3, sc8 = tid & 7;  // staging: 32 rows x 8 chunks per pass

  f32x4 acc[4][4];
#pragma unroll
  for (int i = 0; i < 4; i++)
#pragma unroll
    for (int j = 0; j < 4; j++) acc[i][j] = (f32x4){0.f, 0.f, 0.f, 0.f};

  for (int k0 = 0; k0 < K; k0 += 64) {
    __syncthreads();
#pragma unroll
    for (int it = 0; it < 4; it++) {
      int row = it * 32 + srow;
      int cs = sc8 ^ (row & 7);
      *(uint4*)(&As[row * 64 + cs * 8]) = *(const uint4*)(&A[(m0 + row) * K + k0 + sc8 * 8]);
      *(uint4*)(&Bs[row * 64 + cs * 8]) = *(const uint4*)(&B[(n0 + row) * K + k0 + sc8 * 8]);
    }
    __syncthreads();
#pragma unroll
    for (int kk = 0; kk < 2; kk++) {
      bf16x8 af[4], bf[4];
#pragma unroll
      for (int mt = 0; mt < 4; mt++) {
        int row = wm + mt * 16 + c16;
        int col = (kk * 4 + quad) ^ (row & 7);
        af[mt] = *(const bf16x8*)(&As[row * 64 + col * 8]);
      }
#pragma unroll
      for (int nt = 0; nt < 4; nt++) {
        int row = wn + nt * 16 + c16;
        int col = (kk * 4 + quad) ^ (row & 7);
        bf[nt] = *(const bf16x8*)(&Bs[row * 64 + col * 8]);
      }
#pragma unroll
      for (int mt = 0; mt < 4; mt++)
#pragma unroll
        for (int nt = 0; nt < 4; nt++)
          acc[mt][nt] = __builtin_amdgcn_mfma_f32_16x16x32_bf16(af[mt], bf[nt], acc[mt][nt], 0, 0, 0);
    }
  }
  // epilogue: C/D layout row=(quad*4+r), col=c16 (m89-verified)
#pragma unroll
  for (int mt = 0; mt < 4; mt++)
#pragma unroll
    for (int nt = 0; nt < 4; nt++)
#pragma unroll
      for (int r = 0; r < 4; r++) {
        int m = m0 + wm + mt * 16 + quad * 4 + r;
        int n = n0 + wn + nt * 16 + c16;
        C[m * N + n] = acc[mt][nt][r];
      }
}

// ---------------- RoPE (indexed) + layout + scale folding ----------------
// qkv f32 [2048][4608] -> qB bf16 [32][2048][96] (pre-scaled by SCALE_Q),
//                          kB bf16 [8][2048][96], vtB bf16 [8][96][2048]
__global__ __launch_bounds__(256) void rope_kernel(const float* __restrict__ qkv,
                                                   const float* __restrict__ cosb,
                                                   const float* __restrict__ sinb,
                                                   const int* __restrict__ idxs,
                                                   u16* __restrict__ qB,
                                                   u16* __restrict__ kB,
                                                   u16* __restrict__ vtB) {
  u32 i = blockIdx.x * 256u + threadIdx.x;
  const u32 NQ = 2048u * 32u * 96u;   // 6291456
  const u32 NK = 2048u * 8u * 96u;    // 1572864
  if (i < NQ) {
    u32 s = i / 3072u, rem = i % 3072u;
    u32 h = rem / 96u, d = rem % 96u;
    u32 hkv = h >> 2;
    u32 base = s * 4608u + h * 96u + d;
    float x = qkv[base];
    float pair = (d < 48u) ? -qkv[base + 48u] : qkv[base - 48u];
    int idx = idxs[hkv * 96u + d];
    float c = cosb[s * 128u + idx], sn = sinb[s * 128u + idx];
    qB[(h * 2048u + s) * 96u + d] = f2bf((x * c + pair * sn) * SCALE_Q);
  } else if (i < NQ + NK) {
    u32 j = i - NQ;
    u32 s = j / 768u, rem = j % 768u;
    u32 hkv = rem / 96u, d = rem % 96u;
    u32 base = s * 4608u + 3072u + hkv * 96u + d;
    float x = qkv[base];
    float pair = (d < 48u) ? -qkv[base + 48u] : qkv[base - 48u];
    int idx = idxs[hkv * 96u + d];
    float c = cosb[s * 128u + idx], sn = sinb[s * 128u + idx];
    kB[(hkv * 2048u + s) * 96u + d] = f2bf(x * c + pair * sn);
  } else {
    u32 j = i - NQ - NK;
    u32 s = j / 768u, rem = j % 768u;
    u32 hkv = rem / 96u, d = rem % 96u;
    vtB[(hkv * 96u + d) * 2048u + s] = f2bf(qkv[s * 4608u + 3840u + hkv * 96u + d]);
  }
}

// ---------------- flash-style causal GQA attention ----------------
// grid (32 q-tiles, 32 heads), 256 threads; BLOCK_M=64, K-tile=64.
// Each wave owns 16 q rows. S=Q K^T (q prescaled), online softmax,
// P->LDS roundtrip into A-operand layout, PV with V^T tiles.
__global__ __launch_bounds__(256) void attn_kernel(const u16* __restrict__ qB,
                                                   const u16* __restrict__ kB,
                                                   const u16* __restrict__ vtB,
                                                   u16* __restrict__ aoB) {
  __shared__ u16 Ks[64 * 104];      // rows padded 96->104 (2-way banks = free)
  __shared__ u16 Vs[96 * 72];       // V^T rows padded 64->72
  __shared__ u16 Ps[4 * 16 * 72];   // per-wave P tile, rows padded 64->72
  const int tid = threadIdx.x;
  const int w = tid >> 6, lane = tid & 63, quad = lane >> 4, c16 = lane & 15;
  const int qt = blockIdx.x, h = blockIdx.y, hkv = h >> 2;
  const int m_base = qt * 64 + w * 16;

  bf16x8 qf[3];
  {
    const u16* qrow = qB + (h * 2048 + m_base + c16) * 96;
#pragma unroll
    for (int t = 0; t < 3; t++) qf[t] = *(const bf16x8*)(qrow + t * 32 + quad * 8);
  }
  float m_run[4], l_run[4];
  f32x4 o[6];
#pragma unroll
  for (int r = 0; r < 4; r++) { m_run[r] = -1e30f; l_run[r] = 0.f; }
#pragma unroll
  for (int dt = 0; dt < 6; dt++) o[dt] = (f32x4){0.f, 0.f, 0.f, 0.f};

  u16* pw = Ps + w * (16 * 72);

  for (int kt = 0; kt <= qt; kt++) {
    const int k0 = kt * 64;
    __syncthreads();
    // stage K tile [64][96] -> Ks (768 chunks of 16B)
#pragma unroll
    for (int it = 0; it < 3; it++) {
      int ch = it * 256 + tid;
      int row = ch / 12, c = ch % 12;
      *(uint4*)(&Ks[row * 104 + c * 8]) =
          *(const uint4*)(&kB[(hkv * 2048 + k0 + row) * 96 + c * 8]);
    }
    // stage V^T tile [96][64] -> Vs
#pragma unroll
    for (int it = 0; it < 3; it++) {
      int ch = it * 256 + tid;
      int row = ch >> 3, c = ch & 7;
      *(uint4*)(&Vs[row * 72 + c * 8]) =
          *(const uint4*)(&vtB[(hkv * 96 + row) * 2048 + k0 + c * 8]);
    }
    __syncthreads();

    // S = Q K^T  (16 rows x 64 keys per wave)
    f32x4 sacc[4];
#pragma unroll
    for (int nt = 0; nt < 4; nt++) sacc[nt] = (f32x4){0.f, 0.f, 0.f, 0.f};
#pragma unroll
    for (int nt = 0; nt < 4; nt++)
#pragma unroll
      for (int t = 0; t < 3; t++) {
        bf16x8 kf = *(const bf16x8*)(&Ks[(nt * 16 + c16) * 104 + t * 32 + quad * 8]);
        sacc[nt] = __builtin_amdgcn_mfma_f32_16x16x32_bf16(qf[t], kf, sacc[nt], 0, 0, 0);
      }

    // online softmax (per acc row r; replicated across the 16 lanes of a quad)
#pragma unroll
    for (int r = 0; r < 4; r++) {
      int row_abs = m_base + quad * 4 + r;
      float mx = -1e30f;
#pragma unroll
      for (int nt = 0; nt < 4; nt++) {
        int col = k0 + nt * 16 + c16;
        float v = sacc[nt][r];
        v = (col > row_abs) ? -1e30f : v;
        sacc[nt][r] = v;
        mx = fmaxf(mx, v);
      }
#pragma unroll
      for (int off = 1; off < 16; off <<= 1) mx = fmaxf(mx, __shfl_xor(mx, off, 64));
      float mnew = fmaxf(m_run[r], mx);
      float alpha = __expf(m_run[r] - mnew);
      float rs = 0.f;
#pragma unroll
      for (int nt = 0; nt < 4; nt++) {
        float p = __expf(sacc[nt][r] - mnew);
        sacc[nt][r] = p;
        rs += p;
      }
#pragma unroll
      for (int off = 1; off < 16; off <<= 1) rs += __shfl_xor(rs, off, 64);
      l_run[r] = l_run[r] * alpha + rs;
      m_run[r] = mnew;
#pragma unroll
      for (int dt = 0; dt < 6; dt++) o[dt][r] *= alpha;
    }

    // P (C/D layout) -> per-wave LDS -> A-operand layout
#pragma unroll
    for (int r = 0; r < 4; r++)
#pragma unroll
      for (int nt = 0; nt < 4; nt++)
        pw[(quad * 4 + r) * 72 + nt * 16 + c16] = f2bf(sacc[nt][r]);

    // O += P * V
#pragma unroll
    for (int dt = 0; dt < 6; dt++)
#pragma unroll
      for (int ktile = 0; ktile < 2; ktile++) {
        bf16x8 pf = *(const bf16x8*)(&pw[c16 * 72 + ktile * 32 + quad * 8]);
        bf16x8 vf = *(const bf16x8*)(&Vs[(dt * 16 + c16) * 72 + ktile * 32 + quad * 8]);
        o[dt] = __builtin_amdgcn_mfma_f32_16x16x32_bf16(pf, vf, o[dt], 0, 0, 0);
      }
  }

  // epilogue: normalize, write bf16 to aoB [s][h*96+d]
#pragma unroll
  for (int r = 0; r < 4; r++) {
    float inv = 1.f / l_run[r];
    int row = m_base + quad * 4 + r;
#pragma unroll
    for (int dt = 0; dt < 6; dt++)
      aoB[row * 3072 + h * 96 + dt * 16 + c16] = f2bf(o[dt][r] * inv);
  }
}

// ---------------- host launch ----------------
extern "C" void kernel_launch(void* const* d_in, const int* in_sizes, int n_in,
                              void* d_out, int out_size, void* d_ws, size_t ws_size,
                              hipStream_t stream) {
  const float* hs   = (const float*)d_in[0];
  const float* cosb = (const float*)d_in[1];
  const float* sinb = (const float*)d_in[2];
  const int*   idxs = (const int*)d_in[3];
  const float* Wq   = (const float*)d_in[4];
  const float* Wk   = (const float*)d_in[5];
  const float* Wv   = (const float*)d_in[6];
  const float* Wo   = (const float*)d_in[7];
  float* out = (float*)d_out;
  char* ws = (char*)d_ws;

  // workspace layout (all 16B-aligned)
  u16*   hsB   = (u16*)(ws);                       // 2048*4096 bf16   = 16 MB
  u16*   wqkvB = (u16*)(ws + 16777216);            // 4608*4096 bf16   = 36 MB
  u16*   woB   = (u16*)(ws + 54525952);            // 4096*3072 bf16   = 24 MB
  float* qkvF  = (float*)(ws + 79691776);          // 2048*4608 f32    = 36 MB
  u16*   qB    = (u16*)(ws + 117440512);           // 32*2048*96 bf16  = 12 MB
  u16*   kB    = (u16*)(ws + 130023424);           // 8*2048*96 bf16   = 3 MB
  u16*   vtB   = (u16*)(ws + 133169152);           // 8*96*2048 bf16   = 3 MB
  u16*   aoB   = (u16*)(ws + 136314880);           // 2048*3072 bf16   = 12 MB

  // 1) f32 -> bf16 converts
  cvt_kernel<<<8192, 256, 0, stream>>>(hs, hsB, 2097152);                    // hidden
  cvt_kernel<<<12288, 256, 0, stream>>>(Wq, wqkvB, 3145728);                 // Wq rows 0..3071
  cvt_kernel<<<3072, 256, 0, stream>>>(Wk, wqkvB + 3072 * 4096, 786432);     // Wk rows 3072..3839
  cvt_kernel<<<3072, 256, 0, stream>>>(Wv, wqkvB + 3840 * 4096, 786432);     // Wv rows 3840..4607
  cvt_kernel<<<12288, 256, 0, stream>>>(Wo, woB, 3145728);                   // Wo

  // 2) fused QKV projection: [2048][4608] = hs * Wqkv^T
  gemm_bt<<<dim3(36, 16), 256, 0, stream>>>(hsB, wqkvB, qkvF, 2048, 4608, 4096);

  // 3) indexed RoPE + per-head layout (+SCALE folded into q)
  rope_kernel<<<36864, 256, 0, stream>>>(qkvF, cosb, sinb, idxs, qB, kB, vtB);

  // 4) causal GQA flash attention -> aoB bf16 [2048][3072]
  attn_kernel<<<dim3(32, 32), 256, 0, stream>>>(qB, kB, vtB, aoB);

  // 5) output projection: out[2048][4096] = aoB * Wo^T
  gemm_bt<<<dim3(32, 16), 256, 0, stream>>>(aoB, woB, out, 2048, 4096, 3072);
}